// Round 15
// baseline (122.322 us; speedup 1.0000x reference)
//
#include <hip/hip_runtime.h>
#include <stdint.h>

#define TOKENS 2048
#define HID 1024
#define NE 8

typedef __attribute__((ext_vector_type(8))) short bf16x8;
typedef __attribute__((ext_vector_type(4))) float f32x4;

__device__ __forceinline__ unsigned short f2bf(float f) {
  unsigned int u = __float_as_uint(f);
  return (unsigned short)((u + 0x7fffu + ((u >> 16) & 1u)) >> 16);
}

__device__ __forceinline__ void gload16(const void* g, void* l) {
  __builtin_amdgcn_global_load_lds((const __attribute__((address_space(1))) void*)g,
                                   (__attribute__((address_space(3))) void*)l, 16, 0, 0);
}

// ---------------- k_pre: convert wg/wu (fp32->bf16 + transpose) UNION routing ----------------
__global__ __launch_bounds__(256) void k_pre(
    const float* __restrict__ x, const float* __restrict__ gw,
    const float* __restrict__ wg, const float* __restrict__ wu,
    unsigned short* __restrict__ wgt, unsigned short* __restrict__ wut,
    int* __restrict__ sel, float* __restrict__ rw,
    float* __restrict__ probs, float* __restrict__ ent) {
  __shared__ float tile[64][65];
  const int bid = blockIdx.x;
  const int tid = threadIdx.x;

  if (bid < 4096) {
    const int bx = bid & 15;            // src col tile
    const int by = (bid >> 4) & 15;     // src row tile
    const int e = (bid >> 8) & 7;
    const int tensor = (bid >> 11) & 1;
    const float* src = (tensor == 0 ? wg : wu) + ((size_t)e << 20);
    unsigned short* dst = (tensor == 0 ? wgt : wut) + ((size_t)e << 20);
    const int tr = tid >> 4, tc = (tid & 15) * 4;
#pragma unroll
    for (int p = 0; p < 4; ++p) {
      const int row = p * 16 + tr;
      const float4 v = *(const float4*)(src + (size_t)(by * 64 + row) * 1024 + bx * 64 + tc);
      tile[row][tc] = v.x; tile[row][tc + 1] = v.y; tile[row][tc + 2] = v.z; tile[row][tc + 3] = v.w;
    }
    __syncthreads();
#pragma unroll
    for (int p = 0; p < 4; ++p) {
      const int row = p * 16 + tr;      // dst row (= src col)
      const ushort4 o = make_ushort4(f2bf(tile[tc + 0][row]), f2bf(tile[tc + 1][row]),
                                     f2bf(tile[tc + 2][row]), f2bf(tile[tc + 3][row]));
      *(ushort4*)(dst + (size_t)(bx * 64 + row) * 1024 + by * 64 + tc) = o;
    }
    return;
  }

  // -------- routing: wave-per-token, no atomics --------
  const int w = tid >> 6;
  const int lane = tid & 63;
  const int t = (bid - 4096) * 4 + w;

  const float4* x4 = (const float4*)(x + (size_t)t * HID);
  const float4* gw4 = (const float4*)gw;

  float acc[NE];
#pragma unroll
  for (int e = 0; e < NE; ++e) acc[e] = 0.f;

#pragma unroll
  for (int i = 0; i < 4; ++i) {
    const int idx4 = i * 64 + lane;
    const float4 xv = x4[idx4];
    float4 g[8];
#pragma unroll
    for (int k = 0; k < 8; ++k) g[k] = gw4[(size_t)idx4 * 8 + k];
    const float xs[4] = {xv.x, xv.y, xv.z, xv.w};
#pragma unroll
    for (int c = 0; c < 4; ++c) {
      acc[0] += xs[c] * g[c * 2].x;
      acc[1] += xs[c] * g[c * 2].y;
      acc[2] += xs[c] * g[c * 2].z;
      acc[3] += xs[c] * g[c * 2].w;
      acc[4] += xs[c] * g[c * 2 + 1].x;
      acc[5] += xs[c] * g[c * 2 + 1].y;
      acc[6] += xs[c] * g[c * 2 + 1].z;
      acc[7] += xs[c] * g[c * 2 + 1].w;
    }
  }

#pragma unroll
  for (int e = 0; e < NE; ++e) {
#pragma unroll
    for (int msk = 32; msk >= 1; msk >>= 1) acc[e] += __shfl_xor(acc[e], msk, 64);
  }

  float mx = acc[0];
#pragma unroll
  for (int e = 1; e < NE; ++e) mx = fmaxf(mx, acc[e]);

  const int e8 = lane & 7;
  float my = acc[0];
#pragma unroll
  for (int k = 1; k < NE; ++k) if (e8 == k) my = acc[k];
  const float exl = expf(my - mx);
  float S = exl;
#pragma unroll
  for (int msk = 1; msk <= 4; msk <<= 1) S += __shfl_xor(S, msk, 64);
  const float pp = exl / S;
  if (lane < 8) probs[t * NE + lane] = pp;
  float ev = -pp * logf(pp + 1e-10f);
#pragma unroll
  for (int msk = 1; msk <= 4; msk <<= 1) ev += __shfl_xor(ev, msk, 64);

  if (lane == 0) {
    ent[t] = ev;
    int b0 = 0; float v0 = acc[0];
#pragma unroll
    for (int e = 1; e < NE; ++e) if (acc[e] > v0) { v0 = acc[e]; b0 = e; }
    int b1 = -1; float v1 = 0.f;
#pragma unroll
    for (int e = 0; e < NE; ++e) {
      if (e != b0 && (b1 < 0 || acc[e] > v1)) { v1 = acc[e]; b1 = e; }
    }
    const float w1e = expf(v1 - v0);
    const float s2 = 1.f + w1e;
    sel[t * 2] = b0; sel[t * 2 + 1] = b1;
    rw[t * 2] = 1.f / s2; rw[t * 2 + 1] = w1e / s2;
  }
}

// ---------------- k_aux: lists (blocks 0-7) UNION metrics (block 8) ----------------
__global__ void k_aux(const int* __restrict__ sel, int* __restrict__ cnt,
                      int* __restrict__ hit_list, int* __restrict__ rowidx,
                      const float* __restrict__ probs, const float* __restrict__ ent,
                      float* __restrict__ dout) {
  const int tid = threadIdx.x;

  if (blockIdx.x == 8) {
    __shared__ float red[256][NE];
    __shared__ float rede[256];
    const float4* p4 = (const float4*)probs;
    float pa[NE];
#pragma unroll
    for (int e = 0; e < NE; ++e) pa[e] = 0.f;
    float ea = 0.f;
    for (int t = tid; t < TOKENS; t += 256) {
      const float4 a = p4[t * 2];
      const float4 b = p4[t * 2 + 1];
      pa[0] += a.x; pa[1] += a.y; pa[2] += a.z; pa[3] += a.w;
      pa[4] += b.x; pa[5] += b.y; pa[6] += b.z; pa[7] += b.w;
      ea += ent[t];
    }
#pragma unroll
    for (int e = 0; e < NE; ++e) red[tid][e] = pa[e];
    rede[tid] = ea;
    __syncthreads();
    for (int s = 128; s >= 1; s >>= 1) {
      if (tid < s) {
#pragma unroll
        for (int e = 0; e < NE; ++e) red[tid][e] += red[tid + s][e];
        rede[tid] += rede[tid + s];
      }
      __syncthreads();
    }
    if (tid == 0) {
      float us[NE];
      for (int e = 0; e < NE; ++e) us[e] = red[0][e] / (float)TOKENS;
      float mean = 0.f;
      for (int e = 0; e < NE; ++e) mean += us[e];
      mean /= (float)NE;
      float var = 0.f;
      for (int e = 0; e < NE; ++e) { const float d = us[e] - mean; var += d * d; }
      var /= (float)(NE - 1);
      const float bl = var * (float)NE;
      for (int i = 1; i < NE; ++i) {
        const float key = us[i]; int j = i - 1;
        while (j >= 0 && us[j] > key) { us[j + 1] = us[j]; --j; }
        us[j + 1] = key;
      }
      float num = 0.f, den = 0.f;
      for (int i = 0; i < NE; ++i) { num += (float)(i + 1) * us[i]; den += us[i]; }
      const float gini = 2.f * num / ((float)NE * den) - (float)(NE + 1) / (float)NE;
      dout[(size_t)TOKENS * HID] = bl;
      dout[(size_t)TOKENS * HID + 1] = gini;
      dout[(size_t)TOKENS * HID + 2] = rede[0] / (float)TOKENS;
    }
    return;
  }

  const int e = blockIdx.x;
  __shared__ unsigned long long ssum[256];
  __shared__ unsigned long long csumA[256];
  __shared__ unsigned long long csumB[256];

  int s0[8], s1[8];
  unsigned long long mine = 0ull;
  unsigned long long cA = 0ull, cB = 0ull;
#pragma unroll
  for (int j = 0; j < 8; ++j) {
    const int t = tid * 8 + j;
    s0[j] = sel[2 * t]; s1[j] = sel[2 * t + 1];
#pragma unroll
    for (int q = 0; q < 4; ++q) {
      cA += ((unsigned long long)((s0[j] == q) + (s1[j] == q))) << (16 * q);
      cB += ((unsigned long long)((s0[j] == q + 4) + (s1[j] == q + 4))) << (16 * q);
    }
    const unsigned long long k0 = (s0[j] == e) ? 1ull : 0ull;
    const unsigned long long k1 = (s1[j] == e) ? 1ull : 0ull;
    mine += (k0 | k1) | (k0 << 21) | (k1 << 42);
  }
  ssum[tid] = mine;
  csumA[tid] = cA;
  csumB[tid] = cB;
  __syncthreads();
  for (int s = 128; s >= 1; s >>= 1) {
    if (tid < s) { csumA[tid] += csumA[tid + s]; csumB[tid] += csumB[tid + s]; }
    __syncthreads();
  }
  const unsigned long long totA = csumA[0];
  const unsigned long long totB = csumB[0];
  int tc[NE];
#pragma unroll
  for (int q = 0; q < 4; ++q) {
    tc[q] = (int)((totA >> (16 * q)) & 0xFFFFull);
    tc[q + 4] = (int)((totB >> (16 * q)) & 0xFFFFull);
  }
  if (e == 0 && tid < NE) cnt[tid] = tc[tid];
  int poff = 0;
#pragma unroll
  for (int q = 0; q < NE; ++q) if (q < e) poff += (tc[q] + 127) & ~127;

  for (int s = 1; s < 256; s <<= 1) {
    const unsigned long long v = (tid >= s) ? ssum[tid - s] : 0ull;
    __syncthreads();
    ssum[tid] += v;
    __syncthreads();
  }
  const unsigned long long excl = (tid > 0) ? ssum[tid - 1] : 0ull;
  int hc = (int)(excl & 0x1FFFFFull);
  int c0 = (int)((excl >> 21) & 0x1FFFFFull);
  int c1 = (int)((excl >> 42) & 0x1FFFFFull);
#pragma unroll
  for (int j = 0; j < 8; ++j) {
    const int t = tid * 8 + j;
    const int k0 = (s0[j] == e), k1 = (s1[j] == e);
    if (k0 | k1) { hit_list[poff + hc] = t; ++hc; }
    if (k0) { rowidx[2 * t] = poff + c0; ++c0; }
    if (k1) { rowidx[2 * t + 1] = poff + c1; ++c1; }
  }
}

// ---------------- gather hit rows of x -> bf16 A (8 rows/block) ----------------
__global__ void k_gather(const float* __restrict__ x, const int* __restrict__ hit_list,
                         const int* __restrict__ cnt, unsigned short* __restrict__ A) {
  const int mb = blockIdx.x, e = blockIdx.y;
  const int ce = cnt[e];
  const int pc = (ce + 127) & ~127;
  if (mb * 8 >= pc) return;
  int poff = 0;
  for (int q = 0; q < e; ++q) poff += (cnt[q] + 127) & ~127;
  const int tid = threadIdx.x;
#pragma unroll
  for (int i = 0; i < 8; ++i) {
    const int rr = mb * 8 + i;
    unsigned short* dst = A + (size_t)(poff + rr) * 1024 + tid * 4;
    if (rr < ce) {
      const int t = hit_list[poff + rr];
      const float4 v = *(const float4*)(x + (size_t)t * 1024 + tid * 4);
      *(ushort4*)dst = make_ushort4(f2bf(v.x), f2bf(v.y), f2bf(v.z), f2bf(v.w));
    } else {
      *(ushort4*)dst = make_ushort4(0, 0, 0, 0);
    }
  }
}

// ---------------- GEMM1 + wd-convert rider: z==0 = convert wd (dispatched FIRST);
// ---------------- z=1..8 = GEMM for expert e=z-1 (round-7 proven structure) ----------------
__global__ __launch_bounds__(256, 4) void k_gemm1(
    const unsigned short* __restrict__ A, const unsigned short* __restrict__ wgt,
    const unsigned short* __restrict__ wut, const int* __restrict__ cnt,
    unsigned short* __restrict__ T,
    const float* __restrict__ wd, unsigned short* __restrict__ wdt) {
  __shared__ __align__(16) short lds[3][8192];
  const int tid = threadIdx.x;

  if (blockIdx.z == 0) {
    // -------- wd fp32->bf16 + transpose rider: 8 tiles of 64x64 per block --------
    // Dispatched before the GEMM slices so its 64 MB stream overlaps the GEMM's
    // spare HBM bandwidth instead of serializing at the kernel tail.
    float (*tile)[65] = (float(*)[65])&lds[0][0];   // 16.6 KB < 48 KB
    const int cb = blockIdx.y * 16 + blockIdx.x;    // 0..255
    const int tr = tid >> 4, tc = (tid & 15) * 4;
    for (int i = 0; i < 8; ++i) {
      const int ti = cb * 8 + i;                    // 0..2047
      const int bx = ti & 15, by = (ti >> 4) & 15, e = ti >> 8;
      const float* src = wd + ((size_t)e << 20);
      unsigned short* dst = wdt + ((size_t)e << 20);
#pragma unroll
      for (int p = 0; p < 4; ++p) {
        const int row = p * 16 + tr;
        const float4 v = *(const float4*)(src + (size_t)(by * 64 + row) * 1024 + bx * 64 + tc);
        tile[row][tc] = v.x; tile[row][tc + 1] = v.y; tile[row][tc + 2] = v.z; tile[row][tc + 3] = v.w;
      }
      __syncthreads();
#pragma unroll
      for (int p = 0; p < 4; ++p) {
        const int row = p * 16 + tr;
        const ushort4 o = make_ushort4(f2bf(tile[tc + 0][row]), f2bf(tile[tc + 1][row]),
                                       f2bf(tile[tc + 2][row]), f2bf(tile[tc + 3][row]));
        *(ushort4*)(dst + (size_t)(bx * 64 + row) * 1024 + by * 64 + tc) = o;
      }
      __syncthreads();
    }
    return;
  }

  const int nb = blockIdx.x, mb = blockIdx.y, e = blockIdx.z - 1;
  const int ce = cnt[e];
  if (mb * 128 >= ce) return;
  int poff = 0;
  for (int q = 0; q < e; ++q) poff += (cnt[q] + 127) & ~127;

  const unsigned short* Ab = A + (size_t)(poff + mb * 128) * 1024;
  const unsigned short* Bg = wgt + ((size_t)e << 20) + ((size_t)nb << 16);
  const unsigned short* Bu = wut + ((size_t)e << 20) + ((size_t)nb << 16);

  const int lane = tid & 63;
  const int w = tid >> 6;
  const int wm = w & 1, wn = w >> 1;
  const int r = lane & 15, gq = lane >> 4;
  const int slot = gq ^ ((r >> 1) & 3);
  const int srow = lane >> 2;
  const int skoff = ((lane & 3) ^ ((lane >> 3) & 3)) << 3;

  f32x4 accg[4][2], accu[4][2];
  const f32x4 fz = {0.f, 0.f, 0.f, 0.f};
#pragma unroll
  for (int i = 0; i < 4; ++i)
#pragma unroll
    for (int j = 0; j < 2; ++j) { accg[i][j] = fz; accu[i][j] = fz; }

  auto stage = [&](int kt, int b) {
#pragma unroll
    for (int q = 0; q < 4; ++q) {
      const int gseg = w + q * 4;                 // 0..15
      const unsigned short* sb;
      int seg;
      if (gseg < 8) { sb = Ab; seg = gseg; }
      else if (gseg < 12) { sb = Bg; seg = gseg - 8; }
      else { sb = Bu; seg = gseg - 12; }
      gload16(sb + (size_t)(seg * 16 + srow) * 1024 + kt * 32 + skoff,
              &lds[b][gseg * 512]);
    }
  };

  stage(0, 0); stage(1, 1); stage(2, 2);
  int curb = 0;
  for (int kt = 0; kt < 32; ++kt) {
    if (kt < 30)      { asm volatile("s_waitcnt vmcnt(8)" ::: "memory"); }
    else if (kt == 30){ asm volatile("s_waitcnt vmcnt(4)" ::: "memory"); }
    else              { asm volatile("s_waitcnt vmcnt(0)" ::: "memory"); }
    __builtin_amdgcn_sched_barrier(0);
    __builtin_amdgcn_s_barrier();        // publish tile kt
    __builtin_amdgcn_sched_barrier(0);

    const short* La = &lds[curb][0];
    const short* Lg = &lds[curb][4096];
    const short* Lu = &lds[curb][6144];
    bf16x8 af[4], gf[2], uf[2];
#pragma unroll
    for (int f = 0; f < 4; ++f)
      af[f] = *(const bf16x8*)(La + (wm * 64 + f * 16 + r) * 32 + slot * 8);
#pragma unroll
    for (int f = 0; f < 2; ++f) {
      gf[f] = *(const bf16x8*)(Lg + (wn * 32 + f * 16 + r) * 32 + slot * 8);
      uf[f] = *(const bf16x8*)(Lu + (wn * 32 + f * 16 + r) * 32 + slot * 8);
    }
    asm volatile("s_waitcnt lgkmcnt(0)" ::: "memory");
    __builtin_amdgcn_sched_barrier(0);
    __builtin_amdgcn_s_barrier();        // all waves done reading buffer curb
    __builtin_amdgcn_sched_barrier(0);
    if (kt <= 28) stage(kt + 3, curb);

#pragma unroll
    for (int i = 0; i < 4; ++i)
#pragma unroll
      for (int j = 0; j < 2; ++j) {
        accg[i][j] = __builtin_amdgcn_mfma_f32_16x16x32_bf16(af[i], gf[j], accg[i][j], 0, 0, 0);
        accu[i][j] = __builtin_amdgcn_mfma_f32_16x16x32_bf16(af[i], uf[j], accu[i][j], 0, 0, 0);
      }
    curb = (curb == 2) ? 0 : curb + 1;
  }

  const size_t rowbase = (size_t)(poff + mb * 128);
#pragma unroll
  for (int i = 0; i < 4; ++i)
#pragma unroll
    for (int j = 0; j < 2; ++j) {
      const int col = nb * 64 + wn * 32 + j * 16 + r;
#pragma unroll
      for (int rr = 0; rr < 4; ++rr) {
        const int rowt = wm * 64 + i * 16 + gq * 4 + rr;
        const float gv = accg[i][j][rr];
        const float uv = accu[i][j][rr];
        const float sv = gv / (1.f + expf(-gv)) * uv;
        T[(rowbase + rowt) * 1024 + col] = f2bf(sv);
      }
    }
}

// ---------------- GEMM2 (round-7 proven): Y = T * Wd, bf16 weights -> fp32 ----------------
__global__ __launch_bounds__(256, 4) void k_gemm2(
    const unsigned short* __restrict__ T, const unsigned short* __restrict__ wdt,
    const int* __restrict__ cnt, float* __restrict__ Y) {
  const int nb = blockIdx.x, mb = blockIdx.y, e = blockIdx.z;
  const int ce = cnt[e];
  if (mb * 128 >= ce) return;
  int poff = 0;
  for (int q = 0; q < e; ++q) poff += (cnt[q] + 127) & ~127;

  const unsigned short* Ab = T + (size_t)(poff + mb * 128) * 1024;
  const unsigned short* Bd = wdt + ((size_t)e << 20) + ((size_t)nb << 16);

  __shared__ __align__(16) short lds[3][6144];   // A:8 segs, Bd:4

  const int tid = threadIdx.x;
  const int lane = tid & 63;
  const int w = tid >> 6;
  const int wm = w & 1, wn = w >> 1;
  const int r = lane & 15, gq = lane >> 4;
  const int slot = gq ^ ((r >> 1) & 3);
  const int srow = lane >> 2;
  const int skoff = ((lane & 3) ^ ((lane >> 3) & 3)) << 3;

  f32x4 acc[4][2];
  const f32x4 fz = {0.f, 0.f, 0.f, 0.f};
#pragma unroll
  for (int i = 0; i < 4; ++i)
#pragma unroll
    for (int j = 0; j < 2; ++j) acc[i][j] = fz;

  auto stage = [&](int kt, int b) {
#pragma unroll
    for (int q = 0; q < 3; ++q) {
      const int gseg = w + q * 4;                 // 0..11
      const unsigned short* sb;
      int seg;
      if (gseg < 8) { sb = Ab; seg = gseg; }
      else { sb = Bd; seg = gseg - 8; }
      gload16(sb + (size_t)(seg * 16 + srow) * 1024 + kt * 32 + skoff,
              &lds[b][gseg * 512]);
    }
  };

  stage(0, 0); stage(1, 1); stage(2, 2);
  int curb = 0;
  for (int kt = 0; kt < 32; ++kt) {
    if (kt < 30)      { asm volatile("s_waitcnt vmcnt(6)" ::: "memory"); }
    else if (kt == 30){ asm volatile("s_waitcnt vmcnt(3)" ::: "memory"); }
    else              { asm volatile("s_waitcnt vmcnt(0)" ::: "memory"); }
    __builtin_amdgcn_sched_barrier(0);
    __builtin_amdgcn_s_barrier();        // publish tile kt
    __builtin_amdgcn_sched_barrier(0);

    const short* La = &lds[curb][0];
    const short* Lb = &lds[curb][4096];
    bf16x8 af[4], bfr[2];
#pragma unroll
    for (int f = 0; f < 4; ++f)
      af[f] = *(const bf16x8*)(La + (wm * 64 + f * 16 + r) * 32 + slot * 8);
#pragma unroll
    for (int f = 0; f < 2; ++f)
      bfr[f] = *(const bf16x8*)(Lb + (wn * 32 + f * 16 + r) * 32 + slot * 8);
    asm volatile("s_waitcnt lgkmcnt(0)" ::: "memory");
    __builtin_amdgcn_sched_barrier(0);
    __builtin_amdgcn_s_barrier();        // all reads of buffer curb done
    __builtin_amdgcn_sched_barrier(0);
    if (kt <= 28) stage(kt + 3, curb);

#pragma unroll
    for (int i = 0; i < 4; ++i)
#pragma unroll
      for (int j = 0; j < 2; ++j)
        acc[i][j] = __builtin_amdgcn_mfma_f32_16x16x32_bf16(af[i], bfr[j], acc[i][j], 0, 0, 0);
    curb = (curb == 2) ? 0 : curb + 1;
  }

  const size_t rowbase = (size_t)(poff + mb * 128);
#pragma unroll
  for (int i = 0; i < 4; ++i)
#pragma unroll
    for (int j = 0; j < 2; ++j) {
      const int col = nb * 64 + wn * 32 + j * 16 + r;
#pragma unroll
      for (int rr = 0; rr < 4; ++rr) {
        const int rowt = wm * 64 + i * 16 + gq * 4 + rr;
        Y[(rowbase + rowt) * 1024 + col] = acc[i][j][rr];
      }
    }
}

// ---------------- combine: out[t] = rw0*Y[row0] + rw1*Y[row1] ----------------
__global__ void k_out(const float* __restrict__ Y, const int* __restrict__ rowidx,
                      const float* __restrict__ rw, float* __restrict__ out) {
  const int t = blockIdx.x;
  const int tid = threadIdx.x;
  const int r0 = rowidx[2 * t], r1 = rowidx[2 * t + 1];
  const float w0 = rw[2 * t], w1 = rw[2 * t + 1];
  const float4 y0 = *(const float4*)(Y + (size_t)r0 * HID + tid * 4);
  const float4 y1 = *(const float4*)(Y + (size_t)r1 * HID + tid * 4);
  float4 o;
  o.x = w0 * y0.x + w1 * y1.x;
  o.y = w0 * y0.y + w1 * y1.y;
  o.z = w0 * y0.z + w1 * y1.z;
  o.w = w0 * y0.w + w1 * y1.w;
  *(float4*)(out + (size_t)t * HID + tid * 4) = o;
}

extern "C" void kernel_launch(void* const* d_in, const int* in_sizes, int n_in,
                              void* d_out, int out_size, void* d_ws, size_t ws_size,
                              hipStream_t stream) {
  const float* x = (const float*)d_in[0];
  const float* gw = (const float*)d_in[1];
  const float* wg = (const float*)d_in[2];
  const float* wu = (const float*)d_in[3];
  const float* wd = (const float*)d_in[4];
  float* out = (float*)d_out;

  char* p = (char*)d_ws;
  unsigned short* wgt = (unsigned short*)p;                   // 16 MiB
  unsigned short* wut = (unsigned short*)(p + 16777216);      // 16 MiB
  float* Y = (float*)p;                                       // aliases wgt/wut (dead after gemm1)
  unsigned short* wdt = (unsigned short*)(p + 33554432);      // 16 MiB
  unsigned short* A = (unsigned short*)(p + 50331648);        // 12 MiB
  unsigned short* T = (unsigned short*)(p + 62914560);        // 12 MiB
  char* q = p + 75497472;
  float* probs = (float*)q; q += 65536;
  float* ent = (float*)q; q += 8192;
  int* sel = (int*)q; q += 16384;
  float* rwp = (float*)q; q += 16384;
  int* rowidx = (int*)q; q += 16384;
  int* hit_list = (int*)q; q += 20480;
  int* cnt = (int*)q;

  k_pre<<<4608, 256, 0, stream>>>(x, gw, wg, wu, wgt, wut, sel, rwp, probs, ent);
  k_aux<<<9, 256, 0, stream>>>(sel, cnt, hit_list, rowidx, probs, ent, out);
  k_gather<<<dim3(256, 8), 256, 0, stream>>>(x, hit_list, cnt, A);
  k_gemm1<<<dim3(16, 16, 9), 256, 0, stream>>>(A, wgt, wut, cnt, T, wd, wdt);
  k_gemm2<<<dim3(16, 16, 8), 256, 0, stream>>>(T, wdt, cnt, Y);
  k_out<<<2048, 256, 0, stream>>>(Y, rowidx, rwp, out);
}

// Round 16
// 112.011 us; speedup vs baseline: 1.0920x; 1.0920x over previous
//
#include <hip/hip_runtime.h>
#include <stdint.h>

#define TOKENS 2048
#define HID 1024
#define NE 8

typedef __attribute__((ext_vector_type(8))) short bf16x8;
typedef __attribute__((ext_vector_type(4))) float f32x4;

__device__ __forceinline__ unsigned short f2bf(float f) {
  unsigned int u = __float_as_uint(f);
  return (unsigned short)((u + 0x7fffu + ((u >> 16) & 1u)) >> 16);
}

__device__ __forceinline__ void gload16(const void* g, void* l) {
  __builtin_amdgcn_global_load_lds((const __attribute__((address_space(1))) void*)g,
                                   (__attribute__((address_space(3))) void*)l, 16, 0, 0);
}

// ---------------- routing: wave-per-token, NO global atomics ----------------
__global__ __launch_bounds__(256) void k_rout(
    const float* __restrict__ x, const float* __restrict__ gw,
    int* __restrict__ sel, float* __restrict__ rw,
    float* __restrict__ probs, float* __restrict__ ent) {
  const int w = threadIdx.x >> 6;
  const int lane = threadIdx.x & 63;
  const int t = blockIdx.x * 4 + w;

  const float4* x4 = (const float4*)(x + (size_t)t * HID);
  const float4* gw4 = (const float4*)gw;

  float acc[NE];
#pragma unroll
  for (int e = 0; e < NE; ++e) acc[e] = 0.f;

#pragma unroll
  for (int i = 0; i < 4; ++i) {
    const int idx4 = i * 64 + lane;
    const float4 xv = x4[idx4];
    float4 g[8];
#pragma unroll
    for (int k = 0; k < 8; ++k) g[k] = gw4[(size_t)idx4 * 8 + k];
    const float xs[4] = {xv.x, xv.y, xv.z, xv.w};
#pragma unroll
    for (int c = 0; c < 4; ++c) {
      acc[0] += xs[c] * g[c * 2].x;
      acc[1] += xs[c] * g[c * 2].y;
      acc[2] += xs[c] * g[c * 2].z;
      acc[3] += xs[c] * g[c * 2].w;
      acc[4] += xs[c] * g[c * 2 + 1].x;
      acc[5] += xs[c] * g[c * 2 + 1].y;
      acc[6] += xs[c] * g[c * 2 + 1].z;
      acc[7] += xs[c] * g[c * 2 + 1].w;
    }
  }

#pragma unroll
  for (int e = 0; e < NE; ++e) {
#pragma unroll
    for (int msk = 32; msk >= 1; msk >>= 1) acc[e] += __shfl_xor(acc[e], msk, 64);
  }

  float mx = acc[0];
#pragma unroll
  for (int e = 1; e < NE; ++e) mx = fmaxf(mx, acc[e]);

  const int e8 = lane & 7;
  float my = acc[0];
#pragma unroll
  for (int k = 1; k < NE; ++k) if (e8 == k) my = acc[k];
  const float exl = expf(my - mx);
  float S = exl;
#pragma unroll
  for (int msk = 1; msk <= 4; msk <<= 1) S += __shfl_xor(S, msk, 64);
  const float pp = exl / S;
  if (lane < 8) probs[t * NE + lane] = pp;
  float ev = -pp * logf(pp + 1e-10f);
#pragma unroll
  for (int msk = 1; msk <= 4; msk <<= 1) ev += __shfl_xor(ev, msk, 64);

  if (lane == 0) {
    ent[t] = ev;
    int b0 = 0; float v0 = acc[0];
#pragma unroll
    for (int e = 1; e < NE; ++e) if (acc[e] > v0) { v0 = acc[e]; b0 = e; }
    int b1 = -1; float v1 = 0.f;
#pragma unroll
    for (int e = 0; e < NE; ++e) {
      if (e != b0 && (b1 < 0 || acc[e] > v1)) { v1 = acc[e]; b1 = e; }
    }
    const float w1e = expf(v1 - v0);
    const float s2 = 1.f + w1e;
    sel[t * 2] = b0; sel[t * 2 + 1] = b1;
    rw[t * 2] = 1.f / s2; rw[t * 2 + 1] = w1e / s2;
  }
}

// ---------------- k_aux: lists (blocks 0-7) UNION metrics (block 8) ----------------
__global__ void k_aux(const int* __restrict__ sel, int* __restrict__ cnt,
                      int* __restrict__ hit_list, int* __restrict__ rowidx,
                      const float* __restrict__ probs, const float* __restrict__ ent,
                      float* __restrict__ dout) {
  const int tid = threadIdx.x;

  if (blockIdx.x == 8) {
    __shared__ float red[256][NE];
    __shared__ float rede[256];
    const float4* p4 = (const float4*)probs;
    float pa[NE];
#pragma unroll
    for (int e = 0; e < NE; ++e) pa[e] = 0.f;
    float ea = 0.f;
    for (int t = tid; t < TOKENS; t += 256) {
      const float4 a = p4[t * 2];
      const float4 b = p4[t * 2 + 1];
      pa[0] += a.x; pa[1] += a.y; pa[2] += a.z; pa[3] += a.w;
      pa[4] += b.x; pa[5] += b.y; pa[6] += b.z; pa[7] += b.w;
      ea += ent[t];
    }
#pragma unroll
    for (int e = 0; e < NE; ++e) red[tid][e] = pa[e];
    rede[tid] = ea;
    __syncthreads();
    for (int s = 128; s >= 1; s >>= 1) {
      if (tid < s) {
#pragma unroll
        for (int e = 0; e < NE; ++e) red[tid][e] += red[tid + s][e];
        rede[tid] += rede[tid + s];
      }
      __syncthreads();
    }
    if (tid == 0) {
      float us[NE];
      for (int e = 0; e < NE; ++e) us[e] = red[0][e] / (float)TOKENS;
      float mean = 0.f;
      for (int e = 0; e < NE; ++e) mean += us[e];
      mean /= (float)NE;
      float var = 0.f;
      for (int e = 0; e < NE; ++e) { const float d = us[e] - mean; var += d * d; }
      var /= (float)(NE - 1);
      const float bl = var * (float)NE;
      for (int i = 1; i < NE; ++i) {
        const float key = us[i]; int j = i - 1;
        while (j >= 0 && us[j] > key) { us[j + 1] = us[j]; --j; }
        us[j + 1] = key;
      }
      float num = 0.f, den = 0.f;
      for (int i = 0; i < NE; ++i) { num += (float)(i + 1) * us[i]; den += us[i]; }
      const float gini = 2.f * num / ((float)NE * den) - (float)(NE + 1) / (float)NE;
      dout[(size_t)TOKENS * HID] = bl;
      dout[(size_t)TOKENS * HID + 1] = gini;
      dout[(size_t)TOKENS * HID + 2] = rede[0] / (float)TOKENS;
    }
    return;
  }

  const int e = blockIdx.x;
  __shared__ unsigned long long ssum[256];
  __shared__ unsigned long long csumA[256];
  __shared__ unsigned long long csumB[256];

  int s0[8], s1[8];
  unsigned long long mine = 0ull;
  unsigned long long cA = 0ull, cB = 0ull;
#pragma unroll
  for (int j = 0; j < 8; ++j) {
    const int t = tid * 8 + j;
    s0[j] = sel[2 * t]; s1[j] = sel[2 * t + 1];
#pragma unroll
    for (int q = 0; q < 4; ++q) {
      cA += ((unsigned long long)((s0[j] == q) + (s1[j] == q))) << (16 * q);
      cB += ((unsigned long long)((s0[j] == q + 4) + (s1[j] == q + 4))) << (16 * q);
    }
    const unsigned long long k0 = (s0[j] == e) ? 1ull : 0ull;
    const unsigned long long k1 = (s1[j] == e) ? 1ull : 0ull;
    mine += (k0 | k1) | (k0 << 21) | (k1 << 42);
  }
  ssum[tid] = mine;
  csumA[tid] = cA;
  csumB[tid] = cB;
  __syncthreads();
  for (int s = 128; s >= 1; s >>= 1) {
    if (tid < s) { csumA[tid] += csumA[tid + s]; csumB[tid] += csumB[tid + s]; }
    __syncthreads();
  }
  const unsigned long long totA = csumA[0];
  const unsigned long long totB = csumB[0];
  int tc[NE];
#pragma unroll
  for (int q = 0; q < 4; ++q) {
    tc[q] = (int)((totA >> (16 * q)) & 0xFFFFull);
    tc[q + 4] = (int)((totB >> (16 * q)) & 0xFFFFull);
  }
  if (e == 0 && tid < NE) cnt[tid] = tc[tid];
  int poff = 0;
#pragma unroll
  for (int q = 0; q < NE; ++q) if (q < e) poff += (tc[q] + 127) & ~127;

  for (int s = 1; s < 256; s <<= 1) {
    const unsigned long long v = (tid >= s) ? ssum[tid - s] : 0ull;
    __syncthreads();
    ssum[tid] += v;
    __syncthreads();
  }
  const unsigned long long excl = (tid > 0) ? ssum[tid - 1] : 0ull;
  int hc = (int)(excl & 0x1FFFFFull);
  int c0 = (int)((excl >> 21) & 0x1FFFFFull);
  int c1 = (int)((excl >> 42) & 0x1FFFFFull);
#pragma unroll
  for (int j = 0; j < 8; ++j) {
    const int t = tid * 8 + j;
    const int k0 = (s0[j] == e), k1 = (s1[j] == e);
    if (k0 | k1) { hit_list[poff + hc] = t; ++hc; }
    if (k0) { rowidx[2 * t] = poff + c0; ++c0; }
    if (k1) { rowidx[2 * t + 1] = poff + c1; ++c1; }
  }
}

// ---------------- gather hit rows of x -> bf16 A (8 rows/block) ----------------
__global__ void k_gather(const float* __restrict__ x, const int* __restrict__ hit_list,
                         const int* __restrict__ cnt, unsigned short* __restrict__ A) {
  const int mb = blockIdx.x, e = blockIdx.y;
  const int ce = cnt[e];
  const int pc = (ce + 127) & ~127;
  if (mb * 8 >= pc) return;
  int poff = 0;
  for (int q = 0; q < e; ++q) poff += (cnt[q] + 127) & ~127;
  const int tid = threadIdx.x;
#pragma unroll
  for (int i = 0; i < 8; ++i) {
    const int rr = mb * 8 + i;
    unsigned short* dst = A + (size_t)(poff + rr) * 1024 + tid * 4;
    if (rr < ce) {
      const int t = hit_list[poff + rr];
      const float4 v = *(const float4*)(x + (size_t)t * 1024 + tid * 4);
      *(ushort4*)dst = make_ushort4(f2bf(v.x), f2bf(v.y), f2bf(v.z), f2bf(v.w));
    } else {
      *(ushort4*)dst = make_ushort4(0, 0, 0, 0);
    }
  }
}

// ---------------- GEMM1 (R10 best): T = silu(A*Wg).*(A*Wu); fp32 weights converted in-staging ----------------
__global__ __launch_bounds__(256, 3) void k_gemm1(
    const unsigned short* __restrict__ A, const float* __restrict__ wg,
    const float* __restrict__ wu, const int* __restrict__ cnt,
    unsigned short* __restrict__ T) {
  const int nb = blockIdx.x, mb = blockIdx.y, e = blockIdx.z;
  const int ce = cnt[e];
  if (mb * 128 >= ce) return;
  int poff = 0;
  for (int q = 0; q < e; ++q) poff += (cnt[q] + 127) & ~127;

  const unsigned short* Ab = A + (size_t)(poff + mb * 128) * 1024;
  const float* Wg = wg + ((size_t)e << 20) + nb * 64;
  const float* Wu = wu + ((size_t)e << 20) + nb * 64;

  __shared__ __align__(16) short lds[3][8192];   // per buf: A[0,4096) Wg[4096,6144) Wu[6144,8192)

  const int tid = threadIdx.x;
  const int lane = tid & 63;
  const int w = tid >> 6;
  const int wm = w & 1, wn = w >> 1;
  const int r = lane & 15, gq = lane >> 4;
  const int aslot = gq ^ ((r >> 1) & 3);
  const int wslot = gq ^ ((r >> 2) & 3);
  const int srow = lane >> 2;
  const int skoff = ((lane & 3) ^ ((lane >> 3) & 3)) << 3;
  const int kp = tid >> 4, n4i = tid & 15;

  f32x4 accg[4][2], accu[4][2];
  const f32x4 fz = {0.f, 0.f, 0.f, 0.f};
#pragma unroll
  for (int i = 0; i < 4; ++i)
#pragma unroll
    for (int j = 0; j < 2; ++j) { accg[i][j] = fz; accu[i][j] = fz; }

  auto stageA = [&](int kt, int b) {
#pragma unroll
    for (int q = 0; q < 2; ++q) {
      const int seg = w + q * 4;
      gload16(Ab + (size_t)(seg * 16 + srow) * 1024 + kt * 32 + skoff,
              &lds[b][seg * 512]);
    }
  };
  auto wload = [&](const float* W, int kt, float4& r0, float4& r1) {
    const float* s = W + (size_t)(kt * 32 + 2 * kp) * 1024 + 4 * n4i;
    r0 = *(const float4*)s;
    r1 = *(const float4*)(s + 1024);
  };
  auto wwrite = [&](int b, int base, const float4& lo, const float4& hi) {
    short* Lw = &lds[b][base];
    const float l4[4] = {lo.x, lo.y, lo.z, lo.w};
    const float h4[4] = {hi.x, hi.y, hi.z, hi.w};
#pragma unroll
    for (int j = 0; j < 4; ++j) {
      unsigned int pk;
      asm("v_cvt_pk_bf16_f32 %0, %1, %2" : "=v"(pk) : "v"(l4[j]), "v"(h4[j]));
      const int n = 4 * n4i + j;
      const int ps = (kp >> 2) ^ (n4i & 3);
      *(unsigned int*)(Lw + n * 32 + ps * 8 + (kp & 3) * 2) = pk;
    }
  };

  stageA(0, 0); stageA(1, 1); stageA(2, 2);
  float4 g0A, g1A, u0A, u1A, g0B, g1B, u0B, u1B;
  wload(Wg, 0, g0A, g1A); wload(Wu, 0, u0A, u1A);
  wload(Wg, 1, g0B, g1B); wload(Wu, 1, u0B, u1B);
  wwrite(0, 4096, g0A, g1A); wwrite(0, 6144, u0A, u1A);
  wload(Wg, 2, g0A, g1A); wload(Wu, 2, u0A, u1A);
  wwrite(1, 4096, g0B, g1B); wwrite(1, 6144, u0B, u1B);
  asm volatile("s_waitcnt lgkmcnt(0)" ::: "memory");

  auto iter = [&](int kt, float4& lg0, float4& lg1, float4& lu0, float4& lu1,
                  const float4& sg0, const float4& sg1, const float4& su0, const float4& su1) {
    asm volatile("s_waitcnt vmcnt(12)" ::: "memory");
    __builtin_amdgcn_sched_barrier(0);
    __builtin_amdgcn_s_barrier();
    __builtin_amdgcn_sched_barrier(0);
    const int curb = kt % 3;
    const short* La = &lds[curb][0];
    const short* Lg = &lds[curb][4096];
    const short* Lu = &lds[curb][6144];
    bf16x8 af[4], gf[2], uf[2];
#pragma unroll
    for (int f = 0; f < 4; ++f)
      af[f] = *(const bf16x8*)(La + (wm * 64 + f * 16 + r) * 32 + aslot * 8);
#pragma unroll
    for (int f = 0; f < 2; ++f) {
      gf[f] = *(const bf16x8*)(Lg + (wn * 32 + f * 16 + r) * 32 + wslot * 8);
      uf[f] = *(const bf16x8*)(Lu + (wn * 32 + f * 16 + r) * 32 + wslot * 8);
    }
    asm volatile("s_waitcnt lgkmcnt(0)" ::: "memory");
    __builtin_amdgcn_sched_barrier(0);
    __builtin_amdgcn_s_barrier();
    __builtin_amdgcn_sched_barrier(0);
    if (kt <= 28) {
      wload(Wg, kt + 3, lg0, lg1);
      wload(Wu, kt + 3, lu0, lu1);
      stageA(kt + 3, curb);
    }
    if (kt <= 29) {
      const int wb = (kt + 2) % 3;
      wwrite(wb, 4096, sg0, sg1);
      wwrite(wb, 6144, su0, su1);
    }
#pragma unroll
    for (int i = 0; i < 4; ++i)
#pragma unroll
      for (int j = 0; j < 2; ++j) {
        accg[i][j] = __builtin_amdgcn_mfma_f32_16x16x32_bf16(af[i], gf[j], accg[i][j], 0, 0, 0);
        accu[i][j] = __builtin_amdgcn_mfma_f32_16x16x32_bf16(af[i], uf[j], accu[i][j], 0, 0, 0);
      }
  };

  for (int k2 = 0; k2 < 15; ++k2) {
    iter(2 * k2,     g0B, g1B, u0B, u1B, g0A, g1A, u0A, u1A);
    iter(2 * k2 + 1, g0A, g1A, u0A, u1A, g0B, g1B, u0B, u1B);
  }
#pragma unroll
  for (int kt = 30; kt < 32; ++kt) {
    if (kt == 30) { asm volatile("s_waitcnt vmcnt(6)" ::: "memory"); }
    else          { asm volatile("s_waitcnt vmcnt(0)" ::: "memory"); }
    __builtin_amdgcn_sched_barrier(0);
    __builtin_amdgcn_s_barrier();
    __builtin_amdgcn_sched_barrier(0);
    const int curb = kt % 3;
    const short* La = &lds[curb][0];
    const short* Lg = &lds[curb][4096];
    const short* Lu = &lds[curb][6144];
    bf16x8 af[4], gf[2], uf[2];
#pragma unroll
    for (int f = 0; f < 4; ++f)
      af[f] = *(const bf16x8*)(La + (wm * 64 + f * 16 + r) * 32 + aslot * 8);
#pragma unroll
    for (int f = 0; f < 2; ++f) {
      gf[f] = *(const bf16x8*)(Lg + (wn * 32 + f * 16 + r) * 32 + wslot * 8);
      uf[f] = *(const bf16x8*)(Lu + (wn * 32 + f * 16 + r) * 32 + wslot * 8);
    }
    asm volatile("s_waitcnt lgkmcnt(0)" ::: "memory");
    __builtin_amdgcn_sched_barrier(0);
    __builtin_amdgcn_s_barrier();
    __builtin_amdgcn_sched_barrier(0);
#pragma unroll
    for (int i = 0; i < 4; ++i)
#pragma unroll
      for (int j = 0; j < 2; ++j) {
        accg[i][j] = __builtin_amdgcn_mfma_f32_16x16x32_bf16(af[i], gf[j], accg[i][j], 0, 0, 0);
        accu[i][j] = __builtin_amdgcn_mfma_f32_16x16x32_bf16(af[i], uf[j], accu[i][j], 0, 0, 0);
      }
  }

  const size_t rowbase = (size_t)(poff + mb * 128);
#pragma unroll
  for (int i = 0; i < 4; ++i)
#pragma unroll
    for (int j = 0; j < 2; ++j) {
      const int col = nb * 64 + wn * 32 + j * 16 + r;
#pragma unroll
      for (int rr = 0; rr < 4; ++rr) {
        const int rowt = wm * 64 + i * 16 + gq * 4 + rr;
        const float gv = accg[i][j][rr];
        const float uv = accu[i][j][rr];
        const float sv = gv / (1.f + expf(-gv)) * uv;
        T[(rowbase + rowt) * 1024 + col] = f2bf(sv);
      }
    }
}

// ---------------- GEMM2 (R10 best): Y = T * Wd; fp32 wd converted in-staging -> fp32 Y ----------------
__global__ __launch_bounds__(256, 4) void k_gemm2(
    const unsigned short* __restrict__ T, const float* __restrict__ wd,
    const int* __restrict__ cnt, float* __restrict__ Y) {
  const int nb = blockIdx.x, mb = blockIdx.y, e = blockIdx.z;
  const int ce = cnt[e];
  if (mb * 128 >= ce) return;
  int poff = 0;
  for (int q = 0; q < e; ++q) poff += (cnt[q] + 127) & ~127;

  const unsigned short* Ab = T + (size_t)(poff + mb * 128) * 1024;
  const float* Wd = wd + ((size_t)e << 20) + nb * 64;

  __shared__ __align__(16) short lds[3][6144];   // per buf: A[0,4096) Wd[4096,6144)

  const int tid = threadIdx.x;
  const int lane = tid & 63;
  const int w = tid >> 6;
  const int wm = w & 1, wn = w >> 1;
  const int r = lane & 15, gq = lane >> 4;
  const int aslot = gq ^ ((r >> 1) & 3);
  const int wslot = gq ^ ((r >> 2) & 3);
  const int srow = lane >> 2;
  const int skoff = ((lane & 3) ^ ((lane >> 3) & 3)) << 3;
  const int kp = tid >> 4, n4i = tid & 15;

  f32x4 acc[4][2];
  const f32x4 fz = {0.f, 0.f, 0.f, 0.f};
#pragma unroll
  for (int i = 0; i < 4; ++i)
#pragma unroll
    for (int j = 0; j < 2; ++j) acc[i][j] = fz;

  auto stageA = [&](int kt, int b) {
#pragma unroll
    for (int q = 0; q < 2; ++q) {
      const int seg = w + q * 4;
      gload16(Ab + (size_t)(seg * 16 + srow) * 1024 + kt * 32 + skoff,
              &lds[b][seg * 512]);
    }
  };
  auto wload = [&](int kt, float4& r0, float4& r1) {
    const float* s = Wd + (size_t)(kt * 32 + 2 * kp) * 1024 + 4 * n4i;
    r0 = *(const float4*)s;
    r1 = *(const float4*)(s + 1024);
  };
  auto wwrite = [&](int b, const float4& lo, const float4& hi) {
    short* Lw = &lds[b][4096];
    const float l4[4] = {lo.x, lo.y, lo.z, lo.w};
    const float h4[4] = {hi.x, hi.y, hi.z, hi.w};
#pragma unroll
    for (int j = 0; j < 4; ++j) {
      unsigned int pk;
      asm("v_cvt_pk_bf16_f32 %0, %1, %2" : "=v"(pk) : "v"(l4[j]), "v"(h4[j]));
      const int n = 4 * n4i + j;
      const int ps = (kp >> 2) ^ (n4i & 3);
      *(unsigned int*)(Lw + n * 32 + ps * 8 + (kp & 3) * 2) = pk;
    }
  };

  stageA(0, 0); stageA(1, 1); stageA(2, 2);
  float4 d0A, d1A, d0B, d1B;
  wload(0, d0A, d1A);
  wload(1, d0B, d1B);
  wwrite(0, d0A, d1A);
  wload(2, d0A, d1A);
  wwrite(1, d0B, d1B);
  asm volatile("s_waitcnt lgkmcnt(0)" ::: "memory");

  auto iter = [&](int kt, float4& l0, float4& l1, const float4& s0, const float4& s1) {
    asm volatile("s_waitcnt vmcnt(8)" ::: "memory");
    __builtin_amdgcn_sched_barrier(0);
    __builtin_amdgcn_s_barrier();
    __builtin_amdgcn_sched_barrier(0);
    const int curb = kt % 3;
    const short* La = &lds[curb][0];
    const short* Lb = &lds[curb][4096];
    bf16x8 af[4], bfr[2];
#pragma unroll
    for (int f = 0; f < 4; ++f)
      af[f] = *(const bf16x8*)(La + (wm * 64 + f * 16 + r) * 32 + aslot * 8);
#pragma unroll
    for (int f = 0; f < 2; ++f)
      bfr[f] = *(const bf16x8*)(Lb + (wn * 32 + f * 16 + r) * 32 + wslot * 8);
    asm volatile("s_waitcnt lgkmcnt(0)" ::: "memory");
    __builtin_amdgcn_sched_barrier(0);
    __builtin_amdgcn_s_barrier();
    __builtin_amdgcn_sched_barrier(0);
    if (kt <= 28) {
      wload(kt + 3, l0, l1);
      stageA(kt + 3, curb);
    }
    if (kt <= 29) {
      wwrite((kt + 2) % 3, s0, s1);
    }
#pragma unroll
    for (int i = 0; i < 4; ++i)
#pragma unroll
      for (int j = 0; j < 2; ++j)
        acc[i][j] = __builtin_amdgcn_mfma_f32_16x16x32_bf16(af[i], bfr[j], acc[i][j], 0, 0, 0);
  };

  for (int k2 = 0; k2 < 15; ++k2) {
    iter(2 * k2,     d0B, d1B, d0A, d1A);
    iter(2 * k2 + 1, d0A, d1A, d0B, d1B);
  }
#pragma unroll
  for (int kt = 30; kt < 32; ++kt) {
    if (kt == 30) { asm volatile("s_waitcnt vmcnt(4)" ::: "memory"); }
    else          { asm volatile("s_waitcnt vmcnt(0)" ::: "memory"); }
    __builtin_amdgcn_sched_barrier(0);
    __builtin_amdgcn_s_barrier();
    __builtin_amdgcn_sched_barrier(0);
    const int curb = kt % 3;
    const short* La = &lds[curb][0];
    const short* Lb = &lds[curb][4096];
    bf16x8 af[4], bfr[2];
#pragma unroll
    for (int f = 0; f < 4; ++f)
      af[f] = *(const bf16x8*)(La + (wm * 64 + f * 16 + r) * 32 + aslot * 8);
#pragma unroll
    for (int f = 0; f < 2; ++f)
      bfr[f] = *(const bf16x8*)(Lb + (wn * 32 + f * 16 + r) * 32 + wslot * 8);
    asm volatile("s_waitcnt lgkmcnt(0)" ::: "memory");
    __builtin_amdgcn_sched_barrier(0);
    __builtin_amdgcn_s_barrier();
    __builtin_amdgcn_sched_barrier(0);
#pragma unroll
    for (int i = 0; i < 4; ++i)
#pragma unroll
      for (int j = 0; j < 2; ++j)
        acc[i][j] = __builtin_amdgcn_mfma_f32_16x16x32_bf16(af[i], bfr[j], acc[i][j], 0, 0, 0);
  }

  const size_t rowbase = (size_t)(poff + mb * 128);
#pragma unroll
  for (int i = 0; i < 4; ++i)
#pragma unroll
    for (int j = 0; j < 2; ++j) {
      const int col = nb * 64 + wn * 32 + j * 16 + r;
#pragma unroll
      for (int rr = 0; rr < 4; ++rr) {
        const int rowt = wm * 64 + i * 16 + gq * 4 + rr;
        Y[(rowbase + rowt) * 1024 + col] = acc[i][j][rr];
      }
    }
}

// ---------------- combine: out[t] = rw0*Y[row0] + rw1*Y[row1] ----------------
__global__ void k_out(const float* __restrict__ Y, const int* __restrict__ rowidx,
                      const float* __restrict__ rw, float* __restrict__ out) {
  const int t = blockIdx.x;
  const int tid = threadIdx.x;
  const int r0 = rowidx[2 * t], r1 = rowidx[2 * t + 1];
  const float w0 = rw[2 * t], w1 = rw[2 * t + 1];
  const float4 y0 = *(const float4*)(Y + (size_t)r0 * HID + tid * 4);
  const float4 y1 = *(const float4*)(Y + (size_t)r1 * HID + tid * 4);
  float4 o;
  o.x = w0 * y0.x + w1 * y1.x;
  o.y = w0 * y0.y + w1 * y1.y;
  o.z = w0 * y0.z + w1 * y1.z;
  o.w = w0 * y0.w + w1 * y1.w;
  *(float4*)(out + (size_t)t * HID + tid * 4) = o;
}

extern "C" void kernel_launch(void* const* d_in, const int* in_sizes, int n_in,
                              void* d_out, int out_size, void* d_ws, size_t ws_size,
                              hipStream_t stream) {
  const float* x = (const float*)d_in[0];
  const float* gw = (const float*)d_in[1];
  const float* wg = (const float*)d_in[2];
  const float* wu = (const float*)d_in[3];
  const float* wd = (const float*)d_in[4];
  float* out = (float*)d_out;

  char* p = (char*)d_ws;
  unsigned short* A = (unsigned short*)p;                  // 12 MiB
  unsigned short* T = (unsigned short*)(p + 12582912);     // 12 MiB
  float* Y = (float*)(p + 25165824);                       // 22 MiB fp32
  char* q = p + 48234496;
  float* probs = (float*)q; q += 65536;
  float* ent = (float*)q; q += 8192;
  int* sel = (int*)q; q += 16384;
  float* rwp = (float*)q; q += 16384;
  int* rowidx = (int*)q; q += 16384;
  int* hit_list = (int*)q; q += 20480;
  int* cnt = (int*)q;

  k_rout<<<512, 256, 0, stream>>>(x, gw, sel, rwp, probs, ent);
  k_aux<<<9, 256, 0, stream>>>(sel, cnt, hit_list, rowidx, probs, ent, out);
  k_gather<<<dim3(256, 8), 256, 0, stream>>>(x, hit_list, cnt, A);
  k_gemm1<<<dim3(16, 16, 8), 256, 0, stream>>>(A, wg, wu, cnt, T);
  k_gemm2<<<dim3(16, 16, 8), 256, 0, stream>>>(T, wd, cnt, Y);
  k_out<<<2048, 256, 0, stream>>>(Y, rowidx, rwp, out);
}